// Round 8
// baseline (891.951 us; speedup 1.0000x reference)
//
#include <hip/hip_runtime.h>

#define BB 8
#define CC 256
#define TT 4
#define NNv 4096
#define HH 1024
#define LLv (TT*NNv)   // 16384

typedef short bf16x8 __attribute__((ext_vector_type(8)));
typedef float f32x4 __attribute__((ext_vector_type(4)));

static __device__ __forceinline__ float bfbits2f(unsigned short h) {
    return __uint_as_float(((unsigned int)h) << 16);
}
static __device__ __forceinline__ unsigned short f2bf(float f) {
    unsigned int u = __float_as_uint(f);
    return (unsigned short)((u + 0x7FFFu + ((u >> 16) & 1u)) >> 16);
}
// byte j of a group-of-8 lands at fragment slot p = permpos(j); the spike
// expansion below emits source bytes in order {0,2,4,6,1,3,5,7} at slots 0..7.
static __device__ __forceinline__ int permpos(int j) { return (j >> 1) + ((j & 1) << 2); }

// byte->bf16 {0,1}: slot p holds source byte perm[p], perm = {0,2,4,6,1,3,5,7}
static __device__ __forceinline__ uint4 spikes8_to_bf16(unsigned long long d) {
    unsigned int lo = (unsigned int)d, hi = (unsigned int)(d >> 32);
    uint4 o;
    o.x = (lo & 0x10001u) * 0x3F80u;
    o.y = (hi & 0x10001u) * 0x3F80u;
    o.z = ((lo >> 8) & 0x10001u) * 0x3F80u;
    o.w = ((hi >> 8) & 0x10001u) * 0x3F80u;
    return o;
}

// ---- fc1 weights -> fragment-linear 3-split (hi/mid/lo), k-permuted ----
// dst: ((((ht*4+ko)*2+kb)*4+g)*64 + q*16+ln)*8 + p   (+ s*262144)
__global__ __launch_bounds__(256) void k_prep1(const float* __restrict__ w,
                                               unsigned short* __restrict__ wf)
{
    int i = blockIdx.x * 256 + threadIdx.x;        // i = h*256 + c
    int h = i >> 8, c = i & 255;
    int ht = h >> 6, hr = h & 63, g = hr >> 4, ln = hr & 15;
    int ko = c >> 6, cr = c & 63, kb = cr >> 5, q = (cr >> 3) & 3, j = c & 7;
    size_t base = (((((size_t)ht * 4 + ko) * 2 + kb) * 4 + g) * 64 + q * 16 + ln) * 8 + permpos(j);
    const size_t WS = 262144;
    float x = w[i];
    unsigned short hi = f2bf(x); float r  = __fsub_rn(x, bfbits2f(hi));
    unsigned short md = f2bf(r); float r2 = __fsub_rn(r, bfbits2f(md));
    unsigned short lo = f2bf(r2);
    wf[base] = hi; wf[WS + base] = md; wf[2 * WS + base] = lo;
}

// ---- fc2 weights -> fragment-linear 2-split (hi/lo), k-permuted ----
// dst: ((((ct*8+ko)*4+kb)*4+g)*64 + q*16+ln)*8 + p   (+ s*262144)
__global__ __launch_bounds__(256) void k_prep2(const float* __restrict__ w,
                                               unsigned short* __restrict__ wf)
{
    int i = blockIdx.x * 256 + threadIdx.x;        // i = c*1024 + h
    int c = i >> 10, h = i & 1023;
    int ct = c >> 6, cr = c & 63, g = cr >> 4, ln = cr & 15;
    int ko = h >> 7, hr = h & 127, kb = hr >> 5, q = (hr >> 3) & 3, j = h & 7;
    size_t base = (((((size_t)ct * 8 + ko) * 4 + kb) * 4 + g) * 64 + q * 16 + ln) * 8 + permpos(j);
    const size_t WS = 262144;
    float x = w[i];
    unsigned short hi = f2bf(x); float r = __fsub_rn(x, bfbits2f(hi));
    unsigned short lo = f2bf(r);
    wf[base] = hi; wf[WS + base] = lo;
}

// ---- bn2 + LIF over T + transpose: x[b][c][t][n] -> s1T[bl][t][n][c] bytes ----
__global__ __launch_bounds__(256) void k_bn2_lif_t(
    const float* __restrict__ x,
    const float* __restrict__ g, const float* __restrict__ be,
    const float* __restrict__ mu, const float* __restrict__ va,
    unsigned char* __restrict__ s1T, int b0)
{
    __shared__ unsigned char ts[TT][64][80];       // [t][c][n], stride 80 (16B-aligned)
    int tx = threadIdx.x;
    int n0 = blockIdx.x * 64;
    int c0 = blockIdx.y * 64;
    int bl = blockIdx.z;
    int b  = b0 + bl;
    int cl = tx >> 2, np = tx & 3;
    int c = c0 + cl;
    float rsq = __fdiv_rn(1.0f, __fsqrt_rn(__fadd_rn(va[c], 1e-5f)));
    float inv = __fmul_rn(g[c], rsq);
    float add = __fsub_rn(be[c], __fmul_rn(mu[c], inv));
    size_t xb = ((size_t)(b * CC + c) * TT) * NNv + n0 + np * 16;
    float v[16];
    #pragma unroll
    for (int i = 0; i < 16; i++) v[i] = 0.0f;
    #pragma unroll
    for (int t = 0; t < TT; t++) {
        float4 p[4];
        #pragma unroll
        for (int k = 0; k < 4; k++) p[k] = *(const float4*)(x + xb + (size_t)t * NNv + 4 * k);
        const float* xp = (const float*)p;
        unsigned int ob[4] = {0, 0, 0, 0};
        #pragma unroll
        for (int i = 0; i < 16; i++) {
            float y = __fadd_rn(__fmul_rn(xp[i], inv), add);
            float vv = __fadd_rn(v[i], __fdiv_rn(__fsub_rn(y, v[i]), 1.5f));
            bool sp = vv >= 1.0f;
            v[i] = sp ? 0.0f : vv;
            if (sp) ob[i >> 2] |= 1u << (8 * (i & 3));
        }
        uint4 pk; pk.x = ob[0]; pk.y = ob[1]; pk.z = ob[2]; pk.w = ob[3];
        *(uint4*)&ts[t][cl][np * 16] = pk;
    }
    __syncthreads();
    int nl = tx >> 2, cp = tx & 3;
    #pragma unroll
    for (int t = 0; t < TT; t++) {
        unsigned int u[4];
        #pragma unroll
        for (int kk = 0; kk < 4; kk++) {
            u[kk] = (unsigned int)ts[t][cp * 16 + kk * 4 + 0][nl]
                  | ((unsigned int)ts[t][cp * 16 + kk * 4 + 1][nl] << 8)
                  | ((unsigned int)ts[t][cp * 16 + kk * 4 + 2][nl] << 16)
                  | ((unsigned int)ts[t][cp * 16 + kk * 4 + 3][nl] << 24);
        }
        uint4 pk; pk.x = u[0]; pk.y = u[1]; pk.z = u[2]; pk.w = u[3];
        *(uint4*)(s1T + ((size_t)(bl * TT + t) * NNv + n0 + nl) * CC + c0 + cp * 16) = pk;
    }
}

// ------- GEMM1 (fc1) bf16 3-split, LDS-FREE: per-lane direct spike loads -------
// Each lane's B-fragment = 8 consecutive s1T bytes -> load 8B + expand in-reg.
// No __syncthreads, no LDS: waves are independent dataflows; register
// double-buffer (dc/dn) keeps next phase's loads in flight under MFMA.
__global__ __launch_bounds__(256, 3) void k_gemm1_lif(
    const unsigned short* __restrict__ w1f,
    const float* __restrict__ b1,
    const float* __restrict__ g1, const float* __restrict__ be1,
    const float* __restrict__ mu1, const float* __restrict__ va1,
    const unsigned char* __restrict__ s1T, unsigned char* __restrict__ s2T)
{
    const int tx = threadIdx.x;
    const int n0 = blockIdx.x * 64;
    const int ht = blockIdx.y;
    const int bl = blockIdx.z;
    const int lane = tx & 63, w = tx >> 6;
    const int q = lane >> 4, ln = lane & 15;
    const int mh = (w & 1) * 32, wn = (w >> 1) * 32;
    const int h0 = ht * 64;
    const size_t WS = 262144;

    f32x4 acc[TT][2][2];
    #pragma unroll
    for (int t = 0; t < TT; t++)
    #pragma unroll
    for (int mi = 0; mi < 2; mi++)
    #pragma unroll
    for (int ni = 0; ni < 2; ni++)
        acc[t][mi][ni] = (f32x4){0.f, 0.f, 0.f, 0.f};

    // per-lane spike base: plane t=0, row n0+wn+ln, byte col q*8
    const unsigned char* sb = s1T + ((size_t)(bl * TT) * NNv + (n0 + wn + ln)) * CC + q * 8;
    // compile-time offsets: t plane, ni row-block, (ko,kb) k-chunk
#define SOFF1(t, ni, ko, kb) ((size_t)(t) * NNv * CC + (size_t)(ni) * 16 * CC + (ko) * 64 + (kb) * 32)

    unsigned long long dc[TT][2], dn[TT][2];
    #pragma unroll
    for (int t = 0; t < TT; t++)
    #pragma unroll
    for (int ni = 0; ni < 2; ni++)
        dc[t][ni] = *(const unsigned long long*)(sb + SOFF1(t, ni, 0, 0));

    #pragma unroll
    for (int ph = 0; ph < 8; ph++) {                 // ph = ko*2 + kb
        const int ko = ph >> 1, kb = ph & 1;
        if (ph < 7) {
            const int ko2 = (ph + 1) >> 1, kb2 = (ph + 1) & 1;
            #pragma unroll
            for (int t = 0; t < TT; t++)
            #pragma unroll
            for (int ni = 0; ni < 2; ni++)
                dn[t][ni] = *(const unsigned long long*)(sb + SOFF1(t, ni, ko2, kb2));
        }
        bf16x8 wf[2][3];
        #pragma unroll
        for (int mi = 0; mi < 2; mi++) {
            int gg = (mh >> 4) + mi;
            size_t fbase = (((((size_t)ht * 4 + ko) * 2 + kb) * 4 + gg) * 64 + lane) * 8;
            #pragma unroll
            for (int s = 0; s < 3; s++)
                wf[mi][s] = *(const bf16x8*)(w1f + s * WS + fbase);
        }
        #pragma unroll
        for (int t = 0; t < TT; t++) {
            uint4 e0 = spikes8_to_bf16(dc[t][0]);
            uint4 e1 = spikes8_to_bf16(dc[t][1]);
            bf16x8 sf0 = *(bf16x8*)&e0;
            bf16x8 sf1 = *(bf16x8*)&e1;
            #pragma unroll
            for (int s = 0; s < 3; s++) {
                acc[t][0][0] = __builtin_amdgcn_mfma_f32_16x16x32_bf16(wf[0][s], sf0, acc[t][0][0], 0, 0, 0);
                acc[t][0][1] = __builtin_amdgcn_mfma_f32_16x16x32_bf16(wf[0][s], sf1, acc[t][0][1], 0, 0, 0);
                acc[t][1][0] = __builtin_amdgcn_mfma_f32_16x16x32_bf16(wf[1][s], sf0, acc[t][1][0], 0, 0, 0);
                acc[t][1][1] = __builtin_amdgcn_mfma_f32_16x16x32_bf16(wf[1][s], sf1, acc[t][1][1], 0, 0, 0);
            }
        }
        if (ph < 7) {
            #pragma unroll
            for (int t = 0; t < TT; t++)
            #pragma unroll
            for (int ni = 0; ni < 2; ni++)
                dc[t][ni] = dn[t][ni];
        }
    }
#undef SOFF1

    // epilogue: bias + bn1 + LIF scan over t; packed 4-byte spike stores to s2T[bl][l][h]
    #pragma unroll
    for (int mi = 0; mi < 2; mi++) {
        float invr[4], addr_[4], biasr[4];
        #pragma unroll
        for (int r = 0; r < 4; r++) {
            int h = h0 + mh + mi * 16 + q * 4 + r;
            float rsq = __fdiv_rn(1.0f, __fsqrt_rn(__fadd_rn(va1[h], 1e-5f)));
            invr[r] = __fmul_rn(g1[h], rsq);
            addr_[r] = __fsub_rn(be1[h], __fmul_rn(mu1[h], invr[r]));
            biasr[r] = b1[h];
        }
        #pragma unroll
        for (int ni = 0; ni < 2; ni++) {
            int l_n = n0 + wn + ni * 16 + ln;
            float v4[4] = {0.f, 0.f, 0.f, 0.f};
            #pragma unroll
            for (int t = 0; t < TT; t++) {
                unsigned int pk = 0;
                #pragma unroll
                for (int r = 0; r < 4; r++) {
                    float h1 = __fadd_rn(acc[t][mi][ni][r], biasr[r]);
                    float y  = __fadd_rn(__fmul_rn(h1, invr[r]), addr_[r]);
                    float vv = __fadd_rn(v4[r], __fdiv_rn(__fsub_rn(y, v4[r]), 1.5f));
                    bool sp = vv >= 1.0f;
                    v4[r] = sp ? 0.0f : vv;
                    if (sp) pk |= (1u << (8 * r));
                }
                *(unsigned int*)(s2T + ((size_t)bl * LLv + t * NNv + l_n) * HH
                                 + h0 + mh + mi * 16 + q * 4) = pk;
            }
        }
    }
}

// ------- GEMM2 (fc2) bf16 2-split, LDS-FREE: per-lane direct spike loads -------
__global__ __launch_bounds__(256, 3) void k_gemm2(
    const unsigned short* __restrict__ w2f,
    const float* __restrict__ b2c,
    const unsigned char* __restrict__ s2T, float* __restrict__ outp, int b0)
{
    const int tx = threadIdx.x;
    const int l0 = blockIdx.x * 128;
    const int ct = blockIdx.y;
    const int bl = blockIdx.z;
    const int b  = b0 + bl;
    const int lane = tx & 63, w = tx >> 6;
    const int q = lane >> 4, ln = lane & 15;
    const int mc = (w & 1) * 32, wl = (w >> 1) * 64;
    const size_t WS = 262144;

    f32x4 acc[2][4];
    #pragma unroll
    for (int mi = 0; mi < 2; mi++)
    #pragma unroll
    for (int ni = 0; ni < 4; ni++)
        acc[mi][ni] = (f32x4){0.f, 0.f, 0.f, 0.f};

    const unsigned char* sb = s2T + ((size_t)bl * LLv + l0 + wl + ln) * HH + q * 8;
#define SOFF2(ni, ko, kb) ((size_t)(ni) * 16 * HH + (ko) * 128 + (kb) * 32)

    unsigned long long dc[4], dn[4];
    #pragma unroll
    for (int ni = 0; ni < 4; ni++)
        dc[ni] = *(const unsigned long long*)(sb + SOFF2(ni, 0, 0));

    #pragma unroll
    for (int ph = 0; ph < 32; ph++) {                // ph = ko*4 + kb
        const int ko = ph >> 2, kb = ph & 3;
        if (ph < 31) {
            const int ko2 = (ph + 1) >> 2, kb2 = (ph + 1) & 3;
            #pragma unroll
            for (int ni = 0; ni < 4; ni++)
                dn[ni] = *(const unsigned long long*)(sb + SOFF2(ni, ko2, kb2));
        }
        bf16x8 wf[2][2];
        #pragma unroll
        for (int mi = 0; mi < 2; mi++) {
            int gg = (mc >> 4) + mi;
            size_t fbase = (((((size_t)ct * 8 + ko) * 4 + kb) * 4 + gg) * 64 + lane) * 8;
            #pragma unroll
            for (int s = 0; s < 2; s++)
                wf[mi][s] = *(const bf16x8*)(w2f + s * WS + fbase);
        }
        bf16x8 sf[4];
        #pragma unroll
        for (int ni = 0; ni < 4; ni++) {
            uint4 e = spikes8_to_bf16(dc[ni]);
            sf[ni] = *(bf16x8*)&e;
        }
        #pragma unroll
        for (int s = 0; s < 2; s++)
        #pragma unroll
        for (int mi = 0; mi < 2; mi++)
        #pragma unroll
        for (int ni = 0; ni < 4; ni++)
            acc[mi][ni] = __builtin_amdgcn_mfma_f32_16x16x32_bf16(wf[mi][s], sf[ni], acc[mi][ni], 0, 0, 0);
        if (ph < 31) {
            #pragma unroll
            for (int ni = 0; ni < 4; ni++)
                dc[ni] = dn[ni];
        }
    }
#undef SOFF2

    #pragma unroll
    for (int mi = 0; mi < 2; mi++)
    #pragma unroll
    for (int r = 0; r < 4; r++) {
        int c = ct * 64 + mc + mi * 16 + q * 4 + r;
        float bias = b2c[c];
        #pragma unroll
        for (int ni = 0; ni < 4; ni++) {
            int l = l0 + wl + ni * 16 + ln;
            outp[((size_t)b * CC + c) * LLv + l] = __fadd_rn(acc[mi][ni][r], bias);
        }
    }
}

extern "C" void kernel_launch(void* const* d_in, const int* in_sizes, int n_in,
                              void* d_out, int out_size, void* d_ws, size_t ws_size,
                              hipStream_t stream) {
    const float* x    = (const float*)d_in[0];
    const float* fc1w = (const float*)d_in[1];
    const float* fc1b = (const float*)d_in[2];
    const float* fc2w = (const float*)d_in[3];
    const float* fc2b = (const float*)d_in[4];
    const float* g1   = (const float*)d_in[5];
    const float* be1  = (const float*)d_in[6];
    const float* mu1  = (const float*)d_in[7];
    const float* va1  = (const float*)d_in[8];
    const float* g2   = (const float*)d_in[9];
    const float* be2  = (const float*)d_in[10];
    const float* mu2  = (const float*)d_in[11];
    const float* va2  = (const float*)d_in[12];

    // Workspace layout (ws_size-adaptive; NEVER exceed ws_size — overflow
    // clobbers adjacent input allocations and corrupts x on later calls):
    //   w1f: 3*262144 shorts (1.5 MB)   fc1 weight fragments
    //   w2f: 2*262144 shorts (1.0 MB)   fc2 weight fragments
    //   s1T: (full? 8 : 1) * 4 MB       bn2+LIF spike bytes [b][t][n][c]
    //   s2T: nbc * 16.78 MB             layer-1 spike bytes [bl][l][h]
    const size_t WB  = (size_t)(3 + 2) * 262144 * sizeof(unsigned short); // 2,621,440
    const size_t S1B = (size_t)TT * NNv * CC;                             // 4,194,304 per b
    const size_t S2B = (size_t)LLv * HH;                                  // 16,777,216 per b

    int nbc;          // batch elements per gemm1/gemm2 chunk
    bool full_s1;     // s1T holds all 8 batches (bn2 runs once)?
    if      (ws_size >= WB + 8 * S1B + 8 * S2B) { nbc = 8; full_s1 = true;  }
    else if (ws_size >= WB + 8 * S1B + 4 * S2B) { nbc = 4; full_s1 = true;  }
    else if (ws_size >= WB + 8 * S1B + 2 * S2B) { nbc = 2; full_s1 = true;  }
    else if (ws_size >= WB + 8 * S1B + 1 * S2B) { nbc = 1; full_s1 = true;  }
    else                                        { nbc = 1; full_s1 = false; }

    unsigned short* w1f = (unsigned short*)d_ws;                        // 3*262144 shorts
    unsigned short* w2f = w1f + (size_t)3 * 262144;                     // 2*262144 shorts
    unsigned char*  s1T = (unsigned char*)(w2f + (size_t)2 * 262144);
    unsigned char*  s2T = s1T + (full_s1 ? (size_t)8 * S1B : S1B);
    float* outp = (float*)d_out;

    hipLaunchKernelGGL(k_prep1, dim3(1024), dim3(256), 0, stream, fc1w, w1f);
    hipLaunchKernelGGL(k_prep2, dim3(1024), dim3(256), 0, stream, fc2w, w2f);

    if (full_s1) {
        hipLaunchKernelGGL(k_bn2_lif_t, dim3(NNv / 64, CC / 64, BB), dim3(256), 0, stream,
                           x, g2, be2, mu2, va2, s1T, 0);
        for (int b0 = 0; b0 < BB; b0 += nbc) {
            hipLaunchKernelGGL(k_gemm1_lif, dim3(NNv / 64, HH / 64, nbc), dim3(256), 0, stream,
                               w1f, fc1b, g1, be1, mu1, va1, s1T + (size_t)b0 * S1B, s2T);
            hipLaunchKernelGGL(k_gemm2, dim3(LLv / 128, CC / 64, nbc), dim3(256), 0, stream,
                               w2f, fc2b, s2T, outp, b0);
        }
    } else {
        for (int b0 = 0; b0 < BB; ++b0) {
            hipLaunchKernelGGL(k_bn2_lif_t, dim3(NNv / 64, CC / 64, 1), dim3(256), 0, stream,
                               x, g2, be2, mu2, va2, s1T, b0);
            hipLaunchKernelGGL(k_gemm1_lif, dim3(NNv / 64, HH / 64, 1), dim3(256), 0, stream,
                               w1f, fc1b, g1, be1, mu1, va1, s1T, s2T);
            hipLaunchKernelGGL(k_gemm2, dim3(LLv / 128, CC / 64, 1), dim3(256), 0, stream,
                               w2f, fc2b, s2T, outp, b0);
        }
    }
}

// Round 9
// 674.839 us; speedup vs baseline: 1.3217x; 1.3217x over previous
//
#include <hip/hip_runtime.h>

#define BB 8
#define CC 256
#define TT 4
#define NNv 4096
#define HH 1024
#define LLv (TT*NNv)   // 16384

typedef short bf16x8 __attribute__((ext_vector_type(8)));
typedef float f32x4 __attribute__((ext_vector_type(4)));

static __device__ __forceinline__ float bfbits2f(unsigned short h) {
    return __uint_as_float(((unsigned int)h) << 16);
}
static __device__ __forceinline__ unsigned short f2bf(float f) {
    unsigned int u = __float_as_uint(f);
    return (unsigned short)((u + 0x7FFFu + ((u >> 16) & 1u)) >> 16);
}
// byte j of a group-of-8 lands at fragment slot p = permpos(j); the spike
// expansion below emits source bytes in order {0,2,4,6,1,3,5,7} at slots 0..7.
static __device__ __forceinline__ int permpos(int j) { return (j >> 1) + ((j & 1) << 2); }

// byte->bf16 {0,1}: slot p holds source byte perm[p], perm = {0,2,4,6,1,3,5,7}
static __device__ __forceinline__ uint4 spikes8_to_bf16(unsigned long long d) {
    unsigned int lo = (unsigned int)d, hi = (unsigned int)(d >> 32);
    uint4 o;
    o.x = (lo & 0x10001u) * 0x3F80u;
    o.y = (hi & 0x10001u) * 0x3F80u;
    o.z = ((lo >> 8) & 0x10001u) * 0x3F80u;
    o.w = ((hi >> 8) & 0x10001u) * 0x3F80u;
    return o;
}

// Barrier that does NOT drain vmcnt: LDS ops flushed (lgkmcnt), prefetch
// global loads stay in flight across the barrier. sched_barrier(0) pins
// post-barrier ds ops below the s_barrier (rule #18).
static __device__ __forceinline__ void barrier_keep_vmem() {
    asm volatile("s_waitcnt lgkmcnt(0)" ::: "memory");
    __builtin_amdgcn_s_barrier();
    __builtin_amdgcn_sched_barrier(0);
}

// ---- fc1 weights -> fragment-linear 3-split (hi/mid/lo), k-permuted ----
// dst: ((((ht*4+ko)*2+kb)*4+g)*64 + q*16+ln)*8 + p   (+ s*262144)
__global__ __launch_bounds__(256) void k_prep1(const float* __restrict__ w,
                                               unsigned short* __restrict__ wf)
{
    int i = blockIdx.x * 256 + threadIdx.x;        // i = h*256 + c
    int h = i >> 8, c = i & 255;
    int ht = h >> 6, hr = h & 63, g = hr >> 4, ln = hr & 15;
    int ko = c >> 6, cr = c & 63, kb = cr >> 5, q = (cr >> 3) & 3, j = c & 7;
    size_t base = (((((size_t)ht * 4 + ko) * 2 + kb) * 4 + g) * 64 + q * 16 + ln) * 8 + permpos(j);
    const size_t WS = 262144;
    float x = w[i];
    unsigned short hi = f2bf(x); float r  = __fsub_rn(x, bfbits2f(hi));
    unsigned short md = f2bf(r); float r2 = __fsub_rn(r, bfbits2f(md));
    unsigned short lo = f2bf(r2);
    wf[base] = hi; wf[WS + base] = md; wf[2 * WS + base] = lo;
}

// ---- fc2 weights -> fragment-linear 2-split (hi/lo), k-permuted ----
// dst: ((((ct*8+ko)*4+kb)*4+g)*64 + q*16+ln)*8 + p   (+ s*262144)
__global__ __launch_bounds__(256) void k_prep2(const float* __restrict__ w,
                                               unsigned short* __restrict__ wf)
{
    int i = blockIdx.x * 256 + threadIdx.x;        // i = c*1024 + h
    int c = i >> 10, h = i & 1023;
    int ct = c >> 6, cr = c & 63, g = cr >> 4, ln = cr & 15;
    int ko = h >> 7, hr = h & 127, kb = hr >> 5, q = (hr >> 3) & 3, j = h & 7;
    size_t base = (((((size_t)ct * 8 + ko) * 4 + kb) * 4 + g) * 64 + q * 16 + ln) * 8 + permpos(j);
    const size_t WS = 262144;
    float x = w[i];
    unsigned short hi = f2bf(x); float r = __fsub_rn(x, bfbits2f(hi));
    unsigned short lo = f2bf(r);
    wf[base] = hi; wf[WS + base] = lo;
}

// ---- bn2 + LIF over T + transpose: x[b][c][t][n] -> s1T[bl][t][n][c] bytes ----
__global__ __launch_bounds__(256) void k_bn2_lif_t(
    const float* __restrict__ x,
    const float* __restrict__ g, const float* __restrict__ be,
    const float* __restrict__ mu, const float* __restrict__ va,
    unsigned char* __restrict__ s1T, int b0)
{
    __shared__ unsigned char ts[TT][64][80];       // [t][c][n], stride 80 (16B-aligned)
    int tx = threadIdx.x;
    int n0 = blockIdx.x * 64;
    int c0 = blockIdx.y * 64;
    int bl = blockIdx.z;
    int b  = b0 + bl;
    int cl = tx >> 2, np = tx & 3;
    int c = c0 + cl;
    float rsq = __fdiv_rn(1.0f, __fsqrt_rn(__fadd_rn(va[c], 1e-5f)));
    float inv = __fmul_rn(g[c], rsq);
    float add = __fsub_rn(be[c], __fmul_rn(mu[c], inv));
    size_t xb = ((size_t)(b * CC + c) * TT) * NNv + n0 + np * 16;
    float v[16];
    #pragma unroll
    for (int i = 0; i < 16; i++) v[i] = 0.0f;
    #pragma unroll
    for (int t = 0; t < TT; t++) {
        float4 p[4];
        #pragma unroll
        for (int k = 0; k < 4; k++) p[k] = *(const float4*)(x + xb + (size_t)t * NNv + 4 * k);
        const float* xp = (const float*)p;
        unsigned int ob[4] = {0, 0, 0, 0};
        #pragma unroll
        for (int i = 0; i < 16; i++) {
            float y = __fadd_rn(__fmul_rn(xp[i], inv), add);
            float vv = __fadd_rn(v[i], __fdiv_rn(__fsub_rn(y, v[i]), 1.5f));
            bool sp = vv >= 1.0f;
            v[i] = sp ? 0.0f : vv;
            if (sp) ob[i >> 2] |= 1u << (8 * (i & 3));
        }
        uint4 pk; pk.x = ob[0]; pk.y = ob[1]; pk.z = ob[2]; pk.w = ob[3];
        *(uint4*)&ts[t][cl][np * 16] = pk;
    }
    __syncthreads();
    int nl = tx >> 2, cp = tx & 3;
    #pragma unroll
    for (int t = 0; t < TT; t++) {
        unsigned int u[4];
        #pragma unroll
        for (int kk = 0; kk < 4; kk++) {
            u[kk] = (unsigned int)ts[t][cp * 16 + kk * 4 + 0][nl]
                  | ((unsigned int)ts[t][cp * 16 + kk * 4 + 1][nl] << 8)
                  | ((unsigned int)ts[t][cp * 16 + kk * 4 + 2][nl] << 16)
                  | ((unsigned int)ts[t][cp * 16 + kk * 4 + 3][nl] << 24);
        }
        uint4 pk; pk.x = u[0]; pk.y = u[1]; pk.z = u[2]; pk.w = u[3];
        *(uint4*)(s1T + ((size_t)(bl * TT + t) * NNv + n0 + nl) * CC + c0 + cp * 16) = pk;
    }
}

// ------- GEMM1 (fc1) bf16 3-split, BYTE-LDS + consumer-side expand, bn1+LIF -------
// LDS-pipe fix: spikes staged as raw bytes (18.4KB tile, half the write bytes,
// half the read bytes vs bf16 tile); expansion to bf16 happens after ds_read_b64,
// off the inter-barrier critical path. Reg prefetch + lgkm-only barriers as R7.
__global__ __launch_bounds__(256, 3) void k_gemm1_lif(
    const unsigned short* __restrict__ w1f,
    const float* __restrict__ b1,
    const float* __restrict__ g1, const float* __restrict__ be1,
    const float* __restrict__ mu1, const float* __restrict__ va1,
    const unsigned char* __restrict__ s1T, unsigned char* __restrict__ s2T)
{
    __shared__ unsigned char Ls[TT][64][72];       // 18,432 B byte spikes, +8 skew
    const int tx = threadIdx.x;
    const int n0 = blockIdx.x * 64;
    const int ht = blockIdx.y;
    const int bl = blockIdx.z;
    const int lane = tx & 63, w = tx >> 6;
    const int q = lane >> 4, ln = lane & 15;
    const int mh = (w & 1) * 32, wn = (w >> 1) * 32;
    const int h0 = ht * 64;
    const size_t WS = 262144;

    f32x4 acc[TT][2][2];
    #pragma unroll
    for (int t = 0; t < TT; t++)
    #pragma unroll
    for (int mi = 0; mi < 2; mi++)
    #pragma unroll
    for (int ni = 0; ni < 2; ni++)
        acc[t][mi][ni] = (f32x4){0.f, 0.f, 0.f, 0.f};

    unsigned long long d[2][8];
    #pragma unroll
    for (int i = 0; i < 8; i++) {
        int task = i * 256 + tx;
        int cb = task & 7, nr = (task >> 3) & 63, t = task >> 9;
        d[0][i] = *(const unsigned long long*)(
            s1T + ((size_t)(bl * TT + t) * NNv + n0 + nr) * CC + 0 * 64 + cb * 8);
    }

    #pragma unroll
    for (int ko = 0; ko < 4; ko++) {
        const int cur = ko & 1;
        // protect LDS overwrite: all waves' ds_reads of the previous tile have
        // completed into registers (lgkmcnt(0) inside barrier_keep_vmem)
        if (ko > 0) barrier_keep_vmem();
        #pragma unroll
        for (int i = 0; i < 8; i++) {
            int task = i * 256 + tx;
            int cb = task & 7, nr = (task >> 3) & 63, t = task >> 9;
            *(unsigned long long*)&Ls[t][nr][cb * 8] = d[cur][i];   // raw bytes
        }
        // issue next K-step's global loads; they stay in flight across barriers
        if (ko < 3) {
            #pragma unroll
            for (int i = 0; i < 8; i++) {
                int task = i * 256 + tx;
                int cb = task & 7, nr = (task >> 3) & 63, t = task >> 9;
                d[cur ^ 1][i] = *(const unsigned long long*)(
                    s1T + ((size_t)(bl * TT + t) * NNv + n0 + nr) * CC + (ko + 1) * 64 + cb * 8);
            }
        }
        barrier_keep_vmem();

        #pragma unroll
        for (int kb = 0; kb < 2; kb++) {
            bf16x8 wf[2][3];
            #pragma unroll
            for (int mi = 0; mi < 2; mi++) {
                int gg = (mh >> 4) + mi;
                size_t fbase = (((((size_t)ht * 4 + ko) * 2 + kb) * 4 + gg) * 64 + lane) * 8;
                #pragma unroll
                for (int s = 0; s < 3; s++)
                    wf[mi][s] = *(const bf16x8*)(w1f + s * WS + fbase);
            }
            #pragma unroll
            for (int t = 0; t < TT; t++) {
                unsigned long long r0 = *(const unsigned long long*)&Ls[t][wn + ln][kb * 32 + q * 8];
                unsigned long long r1 = *(const unsigned long long*)&Ls[t][wn + 16 + ln][kb * 32 + q * 8];
                uint4 e0 = spikes8_to_bf16(r0);
                uint4 e1 = spikes8_to_bf16(r1);
                bf16x8 sf0 = *(bf16x8*)&e0;
                bf16x8 sf1 = *(bf16x8*)&e1;
                #pragma unroll
                for (int s = 0; s < 3; s++) {
                    acc[t][0][0] = __builtin_amdgcn_mfma_f32_16x16x32_bf16(wf[0][s], sf0, acc[t][0][0], 0, 0, 0);
                    acc[t][0][1] = __builtin_amdgcn_mfma_f32_16x16x32_bf16(wf[0][s], sf1, acc[t][0][1], 0, 0, 0);
                    acc[t][1][0] = __builtin_amdgcn_mfma_f32_16x16x32_bf16(wf[1][s], sf0, acc[t][1][0], 0, 0, 0);
                    acc[t][1][1] = __builtin_amdgcn_mfma_f32_16x16x32_bf16(wf[1][s], sf1, acc[t][1][1], 0, 0, 0);
                }
            }
        }
    }

    // epilogue: bias + bn1 + LIF scan over t; packed 4-byte spike stores to s2T[bl][l][h]
    #pragma unroll
    for (int mi = 0; mi < 2; mi++) {
        float invr[4], addr_[4], biasr[4];
        #pragma unroll
        for (int r = 0; r < 4; r++) {
            int h = h0 + mh + mi * 16 + q * 4 + r;
            float rsq = __fdiv_rn(1.0f, __fsqrt_rn(__fadd_rn(va1[h], 1e-5f)));
            invr[r] = __fmul_rn(g1[h], rsq);
            addr_[r] = __fsub_rn(be1[h], __fmul_rn(mu1[h], invr[r]));
            biasr[r] = b1[h];
        }
        #pragma unroll
        for (int ni = 0; ni < 2; ni++) {
            int l_n = n0 + wn + ni * 16 + ln;
            float v4[4] = {0.f, 0.f, 0.f, 0.f};
            #pragma unroll
            for (int t = 0; t < TT; t++) {
                unsigned int pk = 0;
                #pragma unroll
                for (int r = 0; r < 4; r++) {
                    float h1 = __fadd_rn(acc[t][mi][ni][r], biasr[r]);
                    float y  = __fadd_rn(__fmul_rn(h1, invr[r]), addr_[r]);
                    float vv = __fadd_rn(v4[r], __fdiv_rn(__fsub_rn(y, v4[r]), 1.5f));
                    bool sp = vv >= 1.0f;
                    v4[r] = sp ? 0.0f : vv;
                    if (sp) pk |= (1u << (8 * r));
                }
                *(unsigned int*)(s2T + ((size_t)bl * LLv + t * NNv + l_n) * HH
                                 + h0 + mh + mi * 16 + q * 4) = pk;
            }
        }
    }
}

// ------- GEMM2 (fc2) bf16 2-split, BYTE-LDS + consumer-side expand, fp32 out -------
__global__ __launch_bounds__(256, 3) void k_gemm2(
    const unsigned short* __restrict__ w2f,
    const float* __restrict__ b2c,
    const unsigned char* __restrict__ s2T, float* __restrict__ outp, int b0)
{
    __shared__ unsigned char Ls[128][152];         // 19,456 B byte spikes, +24 skew
    const int tx = threadIdx.x;
    const int l0 = blockIdx.x * 128;
    const int ct = blockIdx.y;
    const int bl = blockIdx.z;
    const int b  = b0 + bl;
    const int lane = tx & 63, w = tx >> 6;
    const int q = lane >> 4, ln = lane & 15;
    const int mc = (w & 1) * 32, wl = (w >> 1) * 64;
    const size_t WS = 262144;

    f32x4 acc[2][4];
    #pragma unroll
    for (int mi = 0; mi < 2; mi++)
    #pragma unroll
    for (int ni = 0; ni < 4; ni++)
        acc[mi][ni] = (f32x4){0.f, 0.f, 0.f, 0.f};

    unsigned long long d[2][8];
    #pragma unroll
    for (int i = 0; i < 8; i++) {
        int task = i * 256 + tx;
        int hb = task & 15, lr = task >> 4;
        d[0][i] = *(const unsigned long long*)(
            s2T + ((size_t)bl * LLv + l0 + lr) * HH + 0 * 128 + hb * 8);
    }

    #pragma unroll
    for (int ko = 0; ko < 8; ko++) {
        const int cur = ko & 1;
        if (ko > 0) barrier_keep_vmem();
        #pragma unroll
        for (int i = 0; i < 8; i++) {
            int task = i * 256 + tx;
            int hb = task & 15, lr = task >> 4;
            *(unsigned long long*)&Ls[lr][hb * 8] = d[cur][i];     // raw bytes
        }
        if (ko < 7) {
            #pragma unroll
            for (int i = 0; i < 8; i++) {
                int task = i * 256 + tx;
                int hb = task & 15, lr = task >> 4;
                d[cur ^ 1][i] = *(const unsigned long long*)(
                    s2T + ((size_t)bl * LLv + l0 + lr) * HH + (ko + 1) * 128 + hb * 8);
            }
        }
        barrier_keep_vmem();

        #pragma unroll
        for (int kb = 0; kb < 4; kb++) {
            bf16x8 wf[2][2];
            #pragma unroll
            for (int mi = 0; mi < 2; mi++) {
                int gg = (mc >> 4) + mi;
                size_t fbase = (((((size_t)ct * 8 + ko) * 4 + kb) * 4 + gg) * 64 + lane) * 8;
                #pragma unroll
                for (int s = 0; s < 2; s++)
                    wf[mi][s] = *(const bf16x8*)(w2f + s * WS + fbase);
            }
            bf16x8 sf[4];
            #pragma unroll
            for (int ni = 0; ni < 4; ni++) {
                unsigned long long r = *(const unsigned long long*)
                    &Ls[wl + ni * 16 + ln][kb * 32 + q * 8];
                uint4 e = spikes8_to_bf16(r);
                sf[ni] = *(bf16x8*)&e;
            }
            #pragma unroll
            for (int s = 0; s < 2; s++)
            #pragma unroll
            for (int mi = 0; mi < 2; mi++)
            #pragma unroll
            for (int ni = 0; ni < 4; ni++)
                acc[mi][ni] = __builtin_amdgcn_mfma_f32_16x16x32_bf16(wf[mi][s], sf[ni], acc[mi][ni], 0, 0, 0);
        }
    }
    #pragma unroll
    for (int mi = 0; mi < 2; mi++)
    #pragma unroll
    for (int r = 0; r < 4; r++) {
        int c = ct * 64 + mc + mi * 16 + q * 4 + r;
        float bias = b2c[c];
        #pragma unroll
        for (int ni = 0; ni < 4; ni++) {
            int l = l0 + wl + ni * 16 + ln;
            outp[((size_t)b * CC + c) * LLv + l] = __fadd_rn(acc[mi][ni][r], bias);
        }
    }
}

extern "C" void kernel_launch(void* const* d_in, const int* in_sizes, int n_in,
                              void* d_out, int out_size, void* d_ws, size_t ws_size,
                              hipStream_t stream) {
    const float* x    = (const float*)d_in[0];
    const float* fc1w = (const float*)d_in[1];
    const float* fc1b = (const float*)d_in[2];
    const float* fc2w = (const float*)d_in[3];
    const float* fc2b = (const float*)d_in[4];
    const float* g1   = (const float*)d_in[5];
    const float* be1  = (const float*)d_in[6];
    const float* mu1  = (const float*)d_in[7];
    const float* va1  = (const float*)d_in[8];
    const float* g2   = (const float*)d_in[9];
    const float* be2  = (const float*)d_in[10];
    const float* mu2  = (const float*)d_in[11];
    const float* va2  = (const float*)d_in[12];

    // Workspace layout (ws_size-adaptive; NEVER exceed ws_size — overflow
    // clobbers adjacent input allocations and corrupts x on later calls):
    //   w1f: 3*262144 shorts (1.5 MB)   fc1 weight fragments
    //   w2f: 2*262144 shorts (1.0 MB)   fc2 weight fragments
    //   s1T: (full? 8 : 1) * 4 MB       bn2+LIF spike bytes [b][t][n][c]
    //   s2T: nbc * 16.78 MB             layer-1 spike bytes [bl][l][h]
    const size_t WB  = (size_t)(3 + 2) * 262144 * sizeof(unsigned short); // 2,621,440
    const size_t S1B = (size_t)TT * NNv * CC;                             // 4,194,304 per b
    const size_t S2B = (size_t)LLv * HH;                                  // 16,777,216 per b

    int nbc;          // batch elements per gemm1/gemm2 chunk
    bool full_s1;     // s1T holds all 8 batches (bn2 runs once)?
    if      (ws_size >= WB + 8 * S1B + 8 * S2B) { nbc = 8; full_s1 = true;  }
    else if (ws_size >= WB + 8 * S1B + 4 * S2B) { nbc = 4; full_s1 = true;  }
    else if (ws_size >= WB + 8 * S1B + 2 * S2B) { nbc = 2; full_s1 = true;  }
    else if (ws_size >= WB + 8 * S1B + 1 * S2B) { nbc = 1; full_s1 = true;  }
    else                                        { nbc = 1; full_s1 = false; }

    unsigned short* w1f = (unsigned short*)d_ws;                        // 3*262144 shorts
    unsigned short* w2f = w1f + (size_t)3 * 262144;                     // 2*262144 shorts
    unsigned char*  s1T = (unsigned char*)(w2f + (size_t)2 * 262144);
    unsigned char*  s2T = s1T + (full_s1 ? (size_t)8 * S1B : S1B);
    float* outp = (float*)d_out;

    hipLaunchKernelGGL(k_prep1, dim3(1024), dim3(256), 0, stream, fc1w, w1f);
    hipLaunchKernelGGL(k_prep2, dim3(1024), dim3(256), 0, stream, fc2w, w2f);

    if (full_s1) {
        hipLaunchKernelGGL(k_bn2_lif_t, dim3(NNv / 64, CC / 64, BB), dim3(256), 0, stream,
                           x, g2, be2, mu2, va2, s1T, 0);
        for (int b0 = 0; b0 < BB; b0 += nbc) {
            hipLaunchKernelGGL(k_gemm1_lif, dim3(NNv / 64, HH / 64, nbc), dim3(256), 0, stream,
                               w1f, fc1b, g1, be1, mu1, va1, s1T + (size_t)b0 * S1B, s2T);
            hipLaunchKernelGGL(k_gemm2, dim3(LLv / 128, CC / 64, nbc), dim3(256), 0, stream,
                               w2f, fc2b, s2T, outp, b0);
        }
    } else {
        for (int b0 = 0; b0 < BB; ++b0) {
            hipLaunchKernelGGL(k_bn2_lif_t, dim3(NNv / 64, CC / 64, 1), dim3(256), 0, stream,
                               x, g2, be2, mu2, va2, s1T, b0);
            hipLaunchKernelGGL(k_gemm1_lif, dim3(NNv / 64, HH / 64, 1), dim3(256), 0, stream,
                               w1f, fc1b, g1, be1, mu1, va1, s1T, s2T);
            hipLaunchKernelGGL(k_gemm2, dim3(LLv / 128, CC / 64, 1), dim3(256), 0, stream,
                               w2f, fc2b, s2T, outp, b0);
        }
    }
}

// Round 10
// 607.173 us; speedup vs baseline: 1.4690x; 1.1114x over previous
//
#include <hip/hip_runtime.h>

#define BB 8
#define CC 256
#define TT 4
#define NNv 4096
#define HH 1024
#define LLv (TT*NNv)   // 16384

typedef int int4v __attribute__((ext_vector_type(4)));

// Barrier that does NOT drain vmcnt: LDS ops flushed (lgkmcnt), prefetch
// global loads stay in flight across the barrier. sched_barrier(0) pins
// post-barrier ds ops below the s_barrier (rule #18).
static __device__ __forceinline__ void barrier_keep_vmem() {
    asm volatile("s_waitcnt lgkmcnt(0)" ::: "memory");
    __builtin_amdgcn_s_barrier();
    __builtin_amdgcn_sched_barrier(0);
}

// ---- fc1 weights -> 3 signed radix-256 i8 digits, MFMA-fragment-linear ----
// w = (d0*2^16 + d1*2^8 + d2) * 2^-24 exactly (|w|<0.5). Frag block per
// (d, ht64, ko, gg): 64 lanes x 16B; lane = ((c>>4)&3)*16 + (h&15); byte = c&15.
// Mapping verified end-to-end by the R3 i8 kernel (absmax 2e-3).
__global__ __launch_bounds__(256) void k_prep1(const float* __restrict__ w,
                                               unsigned char* __restrict__ wd)
{
    int i = blockIdx.x * 256 + threadIdx.x;        // i = h*256 + c
    int h = i >> 8, c = i & 255;
    int w24 = __float2int_rn(w[i] * 16777216.0f);
    int d2 = ((w24 + 128) & 255) - 128;  w24 = (w24 - d2) >> 8;
    int d1 = ((w24 + 128) & 255) - 128;  w24 = (w24 - d1) >> 8;
    int d0 = w24;
    size_t off = ((((size_t)(h >> 6) * 4 + (c >> 6)) * 4 + ((h >> 4) & 3)) << 10)
               + ((c >> 4) & 3) * 256 + (h & 15) * 16 + (c & 15);
    wd[off] = (unsigned char)d0;
    wd[262144 + off] = (unsigned char)d1;
    wd[2 * 262144 + off] = (unsigned char)d2;
}

// ---- fc2 weights -> 2 signed radix-256 i8 digits ----
// w = (d0*2^8 + d1) * 2^-16. Frag block per (d, ct, ko8, kb2, gg): 64 lanes x 16B,
// lane = ((h>>4)&3)*16 + (c&15), byte = h&15. (R3-verified mapping.)
__global__ __launch_bounds__(256) void k_prep2(const float* __restrict__ w,
                                               unsigned char* __restrict__ wd)
{
    int i = blockIdx.x * 256 + threadIdx.x;        // i = c*1024 + h
    int c = i >> 10, h = i & 1023;
    int w16 = __float2int_rn(w[i] * 65536.0f);
    int d1 = ((w16 + 128) & 255) - 128;  w16 = (w16 - d1) >> 8;
    int d0 = w16;
    size_t off = ((((((size_t)(c >> 6) * 8 + (h >> 7)) * 2 + ((h >> 6) & 1)) * 4
                    + ((c >> 4) & 3)) << 10)
                 + ((h >> 4) & 3) * 256 + (c & 15) * 16 + (h & 15));
    wd[off] = (unsigned char)d0;
    wd[262144 + off] = (unsigned char)d1;
}

// ---- bn2 + LIF over T + transpose: x[b][c][t][n] -> s1T[bl][t][n][c] bytes ----
__global__ __launch_bounds__(256) void k_bn2_lif_t(
    const float* __restrict__ x,
    const float* __restrict__ g, const float* __restrict__ be,
    const float* __restrict__ mu, const float* __restrict__ va,
    unsigned char* __restrict__ s1T, int b0)
{
    __shared__ unsigned char ts[TT][64][80];       // [t][c][n], stride 80 (16B-aligned)
    int tx = threadIdx.x;
    int n0 = blockIdx.x * 64;
    int c0 = blockIdx.y * 64;
    int bl = blockIdx.z;
    int b  = b0 + bl;
    int cl = tx >> 2, np = tx & 3;
    int c = c0 + cl;
    float rsq = __fdiv_rn(1.0f, __fsqrt_rn(__fadd_rn(va[c], 1e-5f)));
    float inv = __fmul_rn(g[c], rsq);
    float add = __fsub_rn(be[c], __fmul_rn(mu[c], inv));
    size_t xb = ((size_t)(b * CC + c) * TT) * NNv + n0 + np * 16;
    float v[16];
    #pragma unroll
    for (int i = 0; i < 16; i++) v[i] = 0.0f;
    #pragma unroll
    for (int t = 0; t < TT; t++) {
        float4 p[4];
        #pragma unroll
        for (int k = 0; k < 4; k++) p[k] = *(const float4*)(x + xb + (size_t)t * NNv + 4 * k);
        const float* xp = (const float*)p;
        unsigned int ob[4] = {0, 0, 0, 0};
        #pragma unroll
        for (int i = 0; i < 16; i++) {
            float y = __fadd_rn(__fmul_rn(xp[i], inv), add);
            float vv = __fadd_rn(v[i], __fdiv_rn(__fsub_rn(y, v[i]), 1.5f));
            bool sp = vv >= 1.0f;
            v[i] = sp ? 0.0f : vv;
            if (sp) ob[i >> 2] |= 1u << (8 * (i & 3));
        }
        uint4 pk; pk.x = ob[0]; pk.y = ob[1]; pk.z = ob[2]; pk.w = ob[3];
        *(uint4*)&ts[t][cl][np * 16] = pk;
    }
    __syncthreads();
    int nl = tx >> 2, cp = tx & 3;
    #pragma unroll
    for (int t = 0; t < TT; t++) {
        unsigned int u[4];
        #pragma unroll
        for (int kk = 0; kk < 4; kk++) {
            u[kk] = (unsigned int)ts[t][cp * 16 + kk * 4 + 0][nl]
                  | ((unsigned int)ts[t][cp * 16 + kk * 4 + 1][nl] << 8)
                  | ((unsigned int)ts[t][cp * 16 + kk * 4 + 2][nl] << 16)
                  | ((unsigned int)ts[t][cp * 16 + kk * 4 + 3][nl] << 24);
        }
        uint4 pk; pk.x = u[0]; pk.y = u[1]; pk.z = u[2]; pk.w = u[3];
        *(uint4*)(s1T + ((size_t)(bl * TT + t) * NNv + n0 + nl) * CC + c0 + cp * 16) = pk;
    }
}

// ------- GEMM1 (fc1) i8 3-digit concurrent, byte-LDS direct, fused bn1+LIF -------
// Tile 64h x 32n x 4t; R7 schedule (reg-prefetch, lgkm-only barriers, single
// buffer). Spikes feed MFMA as raw bytes (no expansion). sf read once per ko
// feeds all 3 digit accs (no re-reads). Exact combine in epilogue.
__global__ __launch_bounds__(256, 3) void k_gemm1_lif(
    const unsigned char* __restrict__ w1d,
    const float* __restrict__ b1,
    const float* __restrict__ g1, const float* __restrict__ be1,
    const float* __restrict__ mu1, const float* __restrict__ va1,
    const unsigned char* __restrict__ s1T, unsigned char* __restrict__ s2T)
{
    __shared__ unsigned char Ls[TT * 32][80];      // 128 rows x 80B = 10,240 B
    const int tx = threadIdx.x;
    const int n0 = blockIdx.x * 32;
    const int ht = blockIdx.y;                     // h0 = ht*64
    const int bl = blockIdx.z;
    const int lane = tx & 63, w = tx >> 6;
    const int q = lane >> 4, ln = lane & 15;
    const int mh = (w & 1) * 32, wn = (w >> 1) * 16;
    const int h0 = ht * 64;

    int4v a0[TT][2], a1[TT][2], a2[TT][2];         // [t][mi] per digit
    #pragma unroll
    for (int t = 0; t < TT; t++)
    #pragma unroll
    for (int mi = 0; mi < 2; mi++) {
        a0[t][mi] = (int4v){0, 0, 0, 0};
        a1[t][mi] = (int4v){0, 0, 0, 0};
        a2[t][mi] = (int4v){0, 0, 0, 0};
    }

    // stage tasks: 4/thread covering 4t x 32n x 64c bytes (1024 x 8B)
    unsigned long long d[2][4];
    #pragma unroll
    for (int i = 0; i < 4; i++) {
        int task = i * 256 + tx;
        int cb = task & 7, nr = (task >> 3) & 31, t = task >> 8;
        d[0][i] = *(const unsigned long long*)(
            s1T + ((size_t)(bl * TT + t) * NNv + n0 + nr) * CC + 0 * 64 + cb * 8);
    }

    #pragma unroll
    for (int ko = 0; ko < 4; ko++) {
        const int cur = ko & 1;
        if (ko > 0) barrier_keep_vmem();           // prior ds_reads done (lgkm 0)
        #pragma unroll
        for (int i = 0; i < 4; i++) {
            int task = i * 256 + tx;
            int cb = task & 7, nr = (task >> 3) & 31, t = task >> 8;
            *(unsigned long long*)&Ls[t * 32 + nr][cb * 8] = d[cur][i];  // raw bytes
        }
        if (ko < 3) {
            #pragma unroll
            for (int i = 0; i < 4; i++) {
                int task = i * 256 + tx;
                int cb = task & 7, nr = (task >> 3) & 31, t = task >> 8;
                d[cur ^ 1][i] = *(const unsigned long long*)(
                    s1T + ((size_t)(bl * TT + t) * NNv + n0 + nr) * CC + (ko + 1) * 64 + cb * 8);
            }
        }
        barrier_keep_vmem();

        int4v sf[TT];
        #pragma unroll
        for (int t = 0; t < TT; t++)
            sf[t] = *(const int4v*)&Ls[t * 32 + wn + ln][q * 16];
        int4v w0[2], w1[2], w2[2];
        #pragma unroll
        for (int mi = 0; mi < 2; mi++) {
            size_t fb = ((((size_t)ht * 4 + ko) * 4 + (mh >> 4) + mi) << 10) + lane * 16;
            w0[mi] = *(const int4v*)(w1d + fb);
            w1[mi] = *(const int4v*)(w1d + 262144 + fb);
            w2[mi] = *(const int4v*)(w1d + 2 * 262144 + fb);
        }
        #pragma unroll
        for (int t = 0; t < TT; t++)
        #pragma unroll
        for (int mi = 0; mi < 2; mi++) {
            a0[t][mi] = __builtin_amdgcn_mfma_i32_16x16x64_i8(w0[mi], sf[t], a0[t][mi], 0, 0, 0);
            a1[t][mi] = __builtin_amdgcn_mfma_i32_16x16x64_i8(w1[mi], sf[t], a1[t][mi], 0, 0, 0);
            a2[t][mi] = __builtin_amdgcn_mfma_i32_16x16x64_i8(w2[mi], sf[t], a2[t][mi], 0, 0, 0);
        }
    }

    // epilogue: exact combine -> f32 (*2^-24), bias + bn1 + LIF, packed stores
    const int l_n = n0 + wn + ln;
    #pragma unroll
    for (int mi = 0; mi < 2; mi++) {
        float invr[4], addr_[4], biasr[4];
        #pragma unroll
        for (int r = 0; r < 4; r++) {
            int h = h0 + mh + mi * 16 + q * 4 + r;
            float rsq = __fdiv_rn(1.0f, __fsqrt_rn(__fadd_rn(va1[h], 1e-5f)));
            invr[r] = __fmul_rn(g1[h], rsq);
            addr_[r] = __fsub_rn(be1[h], __fmul_rn(mu1[h], invr[r]));
            biasr[r] = b1[h];
        }
        float v4[4] = {0.f, 0.f, 0.f, 0.f};
        #pragma unroll
        for (int t = 0; t < TT; t++) {
            int4v ci = (((a0[t][mi] << 8) + a1[t][mi]) << 8) + a2[t][mi];
            unsigned int pk = 0;
            #pragma unroll
            for (int r = 0; r < 4; r++) {
                float h1 = __fadd_rn(__fmul_rn((float)ci[r], 5.9604644775390625e-08f),
                                     biasr[r]);    // 2^-24
                float y  = __fadd_rn(__fmul_rn(h1, invr[r]), addr_[r]);
                float vv = __fadd_rn(v4[r], __fdiv_rn(__fsub_rn(y, v4[r]), 1.5f));
                bool sp = vv >= 1.0f;
                v4[r] = sp ? 0.0f : vv;
                if (sp) pk |= (1u << (8 * r));
            }
            *(unsigned int*)(s2T + ((size_t)bl * LLv + t * NNv + l_n) * HH
                             + h0 + mh + mi * 16 + q * 4) = pk;
        }
    }
}

// ------- GEMM2 (fc2) i8 2-digit concurrent, byte-LDS direct, fp32 out -------
// Tile 64l x 64c, K staged 8 x 128 bytes; R7 schedule; no expansion.
__global__ __launch_bounds__(256, 3) void k_gemm2(
    const unsigned char* __restrict__ w2d,
    const float* __restrict__ b2c,
    const unsigned char* __restrict__ s2T, float* __restrict__ outp, int b0)
{
    __shared__ unsigned char Ls[64][144];          // 9,216 B
    const int tx = threadIdx.x;
    const int l0 = blockIdx.x * 64;
    const int ct = blockIdx.y;
    const int bl = blockIdx.z;
    const int b  = b0 + bl;
    const int lane = tx & 63, w = tx >> 6;
    const int q = lane >> 4, ln = lane & 15;
    const int mc = (w & 1) * 32, wl = (w >> 1) * 32;

    int4v a0[2][2], a1[2][2];                      // [mi][ni] per digit
    #pragma unroll
    for (int mi = 0; mi < 2; mi++)
    #pragma unroll
    for (int ni = 0; ni < 2; ni++) {
        a0[mi][ni] = (int4v){0, 0, 0, 0};
        a1[mi][ni] = (int4v){0, 0, 0, 0};
    }

    // stage tasks: 4/thread covering 64l x 128h bytes (1024 x 8B)
    unsigned long long d[2][4];
    #pragma unroll
    for (int i = 0; i < 4; i++) {
        int task = i * 256 + tx;
        int hb = task & 15, lr = task >> 4;
        d[0][i] = *(const unsigned long long*)(
            s2T + ((size_t)bl * LLv + l0 + lr) * HH + 0 * 128 + hb * 8);
    }

    #pragma unroll
    for (int ko = 0; ko < 8; ko++) {
        const int cur = ko & 1;
        if (ko > 0) barrier_keep_vmem();
        #pragma unroll
        for (int i = 0; i < 4; i++) {
            int task = i * 256 + tx;
            int hb = task & 15, lr = task >> 4;
            *(unsigned long long*)&Ls[lr][hb * 8] = d[cur][i];          // raw bytes
        }
        if (ko < 7) {
            #pragma unroll
            for (int i = 0; i < 4; i++) {
                int task = i * 256 + tx;
                int hb = task & 15, lr = task >> 4;
                d[cur ^ 1][i] = *(const unsigned long long*)(
                    s2T + ((size_t)bl * LLv + l0 + lr) * HH + (ko + 1) * 128 + hb * 8);
            }
        }
        barrier_keep_vmem();

        #pragma unroll
        for (int kb = 0; kb < 2; kb++) {
            int4v sf[2];
            #pragma unroll
            for (int ni = 0; ni < 2; ni++)
                sf[ni] = *(const int4v*)&Ls[wl + ni * 16 + ln][kb * 64 + q * 16];
            int4v w0[2], w1[2];
            #pragma unroll
            for (int mi = 0; mi < 2; mi++) {
                size_t fb = ((((((size_t)ct * 8 + ko) * 2 + kb) * 4 + (mc >> 4) + mi)) << 10)
                          + lane * 16;
                w0[mi] = *(const int4v*)(w2d + fb);
                w1[mi] = *(const int4v*)(w2d + 262144 + fb);
            }
            #pragma unroll
            for (int mi = 0; mi < 2; mi++)
            #pragma unroll
            for (int ni = 0; ni < 2; ni++) {
                a0[mi][ni] = __builtin_amdgcn_mfma_i32_16x16x64_i8(w0[mi], sf[ni], a0[mi][ni], 0, 0, 0);
                a1[mi][ni] = __builtin_amdgcn_mfma_i32_16x16x64_i8(w1[mi], sf[ni], a1[mi][ni], 0, 0, 0);
            }
        }
    }
    #pragma unroll
    for (int mi = 0; mi < 2; mi++)
    #pragma unroll
    for (int ni = 0; ni < 2; ni++) {
        int4v tv = (a0[mi][ni] << 8) + a1[mi][ni];
        #pragma unroll
        for (int r = 0; r < 4; r++) {
            int c = ct * 64 + mc + mi * 16 + q * 4 + r;
            int l = l0 + wl + ni * 16 + ln;
            outp[((size_t)b * CC + c) * LLv + l] =
                __fadd_rn(__fmul_rn((float)tv[r], 1.52587890625e-05f), b2c[c]); // 2^-16
        }
    }
}

extern "C" void kernel_launch(void* const* d_in, const int* in_sizes, int n_in,
                              void* d_out, int out_size, void* d_ws, size_t ws_size,
                              hipStream_t stream) {
    const float* x    = (const float*)d_in[0];
    const float* fc1w = (const float*)d_in[1];
    const float* fc1b = (const float*)d_in[2];
    const float* fc2w = (const float*)d_in[3];
    const float* fc2b = (const float*)d_in[4];
    const float* g1   = (const float*)d_in[5];
    const float* be1  = (const float*)d_in[6];
    const float* mu1  = (const float*)d_in[7];
    const float* va1  = (const float*)d_in[8];
    const float* g2   = (const float*)d_in[9];
    const float* be2  = (const float*)d_in[10];
    const float* mu2  = (const float*)d_in[11];
    const float* va2  = (const float*)d_in[12];

    // Workspace layout (ws_size-adaptive; NEVER exceed ws_size — overflow
    // clobbers adjacent input allocations and corrupts x on later calls):
    //   w1d: 3*262144 i8 digits (768 KB)
    //   w2d: 2*262144 i8 digits (512 KB)
    //   s1T: (full? 8 : 1) * 4 MB      bn2+LIF spike bytes [b][t][n][c]
    //   s2T: nbc * 16.78 MB            layer-1 spike bytes [bl][l][h]
    const size_t WB  = (size_t)3 * 262144 + (size_t)2 * 262144;          // 1,310,720
    const size_t S1B = (size_t)TT * NNv * CC;                            // 4,194,304 per b
    const size_t S2B = (size_t)LLv * HH;                                 // 16,777,216 per b

    int nbc;          // batch elements per gemm1/gemm2 chunk
    bool full_s1;     // s1T holds all 8 batches (bn2 runs once)?
    if      (ws_size >= WB + 8 * S1B + 8 * S2B) { nbc = 8; full_s1 = true;  }
    else if (ws_size >= WB + 8 * S1B + 4 * S2B) { nbc = 4; full_s1 = true;  }
    else if (ws_size >= WB + 8 * S1B + 2 * S2B) { nbc = 2; full_s1 = true;  }
    else if (ws_size >= WB + 8 * S1B + 1 * S2B) { nbc = 1; full_s1 = true;  }
    else                                        { nbc = 1; full_s1 = false; }

    unsigned char* w1d = (unsigned char*)d_ws;
    unsigned char* w2d = w1d + (size_t)3 * 262144;
    unsigned char* s1T = w2d + (size_t)2 * 262144;
    unsigned char* s2T = s1T + (full_s1 ? (size_t)8 * S1B : S1B);
    float* outp = (float*)d_out;

    hipLaunchKernelGGL(k_prep1, dim3(1024), dim3(256), 0, stream, fc1w, w1d);
    hipLaunchKernelGGL(k_prep2, dim3(1024), dim3(256), 0, stream, fc2w, w2d);

    if (full_s1) {
        hipLaunchKernelGGL(k_bn2_lif_t, dim3(NNv / 64, CC / 64, BB), dim3(256), 0, stream,
                           x, g2, be2, mu2, va2, s1T, 0);
        for (int b0 = 0; b0 < BB; b0 += nbc) {
            hipLaunchKernelGGL(k_gemm1_lif, dim3(NNv / 32, HH / 64, nbc), dim3(256), 0, stream,
                               w1d, fc1b, g1, be1, mu1, va1, s1T + (size_t)b0 * S1B, s2T);
            hipLaunchKernelGGL(k_gemm2, dim3(LLv / 64, CC / 64, nbc), dim3(256), 0, stream,
                               w2d, fc2b, s2T, outp, b0);
        }
    } else {
        for (int b0 = 0; b0 < BB; ++b0) {
            hipLaunchKernelGGL(k_bn2_lif_t, dim3(NNv / 64, CC / 64, 1), dim3(256), 0, stream,
                               x, g2, be2, mu2, va2, s1T, b0);
            hipLaunchKernelGGL(k_gemm1_lif, dim3(NNv / 32, HH / 64, 1), dim3(256), 0, stream,
                               w1d, fc1b, g1, be1, mu1, va1, s1T, s2T);
            hipLaunchKernelGGL(k_gemm2, dim3(LLv / 64, CC / 64, 1), dim3(256), 0, stream,
                               w2d, fc2b, s2T, outp, b0);
        }
    }
}

// Round 11
// 542.920 us; speedup vs baseline: 1.6429x; 1.1183x over previous
//
#include <hip/hip_runtime.h>

#define BB 8
#define CC 256
#define TT 4
#define NNv 4096
#define HH 1024
#define LLv (TT*NNv)   // 16384

typedef int int4v __attribute__((ext_vector_type(4)));

// Barrier that does NOT drain vmcnt: LDS ops flushed (lgkmcnt), prefetch
// global loads stay in flight across the barrier. sched_barrier(0) pins
// post-barrier ds ops below the s_barrier (rule #18).
static __device__ __forceinline__ void barrier_keep_vmem() {
    asm volatile("s_waitcnt lgkmcnt(0)" ::: "memory");
    __builtin_amdgcn_s_barrier();
    __builtin_amdgcn_sched_barrier(0);
}

// ---- fc1 weights -> 3 signed radix-256 i8 digits, MFMA-fragment-linear ----
// w = (d0*2^16 + d1*2^8 + d2) * 2^-24 exactly (|w|<0.5). Frag block per
// (d, ht64, ko, gg): 64 lanes x 16B; lane = ((c>>4)&3)*16 + (h&15); byte = c&15.
// Mapping verified end-to-end (R3/R10 i8 kernels, absmax 2e-3).
__global__ __launch_bounds__(256) void k_prep1(const float* __restrict__ w,
                                               unsigned char* __restrict__ wd)
{
    int i = blockIdx.x * 256 + threadIdx.x;        // i = h*256 + c
    int h = i >> 8, c = i & 255;
    int w24 = __float2int_rn(w[i] * 16777216.0f);
    int d2 = ((w24 + 128) & 255) - 128;  w24 = (w24 - d2) >> 8;
    int d1 = ((w24 + 128) & 255) - 128;  w24 = (w24 - d1) >> 8;
    int d0 = w24;
    size_t off = ((((size_t)(h >> 6) * 4 + (c >> 6)) * 4 + ((h >> 4) & 3)) << 10)
               + ((c >> 4) & 3) * 256 + (h & 15) * 16 + (c & 15);
    wd[off] = (unsigned char)d0;
    wd[262144 + off] = (unsigned char)d1;
    wd[2 * 262144 + off] = (unsigned char)d2;
}

// ---- fc2 weights -> 2 signed radix-256 i8 digits ----
// w = (d0*2^8 + d1) * 2^-16. Frag block per (d, c64, ko8, kb2, gg): 64 lanes x
// 16B, lane = ((h>>4)&3)*16 + (c&15), byte = h&15. (R3/R10-verified mapping.)
__global__ __launch_bounds__(256) void k_prep2(const float* __restrict__ w,
                                               unsigned char* __restrict__ wd)
{
    int i = blockIdx.x * 256 + threadIdx.x;        // i = c*1024 + h
    int c = i >> 10, h = i & 1023;
    int w16 = __float2int_rn(w[i] * 65536.0f);
    int d1 = ((w16 + 128) & 255) - 128;  w16 = (w16 - d1) >> 8;
    int d0 = w16;
    size_t off = ((((((size_t)(c >> 6) * 8 + (h >> 7)) * 2 + ((h >> 6) & 1)) * 4
                    + ((c >> 4) & 3)) << 10)
                 + ((h >> 4) & 3) * 256 + (c & 15) * 16 + (h & 15));
    wd[off] = (unsigned char)d0;
    wd[262144 + off] = (unsigned char)d1;
}

// ---- bn2 + LIF over T + transpose: x[b][c][t][n] -> s1T[bl][t][n][c] bytes ----
__global__ __launch_bounds__(256) void k_bn2_lif_t(
    const float* __restrict__ x,
    const float* __restrict__ g, const float* __restrict__ be,
    const float* __restrict__ mu, const float* __restrict__ va,
    unsigned char* __restrict__ s1T, int b0)
{
    __shared__ unsigned char ts[TT][64][80];       // [t][c][n], stride 80 (16B-aligned)
    int tx = threadIdx.x;
    int n0 = blockIdx.x * 64;
    int c0 = blockIdx.y * 64;
    int bl = blockIdx.z;
    int b  = b0 + bl;
    int cl = tx >> 2, np = tx & 3;
    int c = c0 + cl;
    float rsq = __fdiv_rn(1.0f, __fsqrt_rn(__fadd_rn(va[c], 1e-5f)));
    float inv = __fmul_rn(g[c], rsq);
    float add = __fsub_rn(be[c], __fmul_rn(mu[c], inv));
    size_t xb = ((size_t)(b * CC + c) * TT) * NNv + n0 + np * 16;
    float v[16];
    #pragma unroll
    for (int i = 0; i < 16; i++) v[i] = 0.0f;
    #pragma unroll
    for (int t = 0; t < TT; t++) {
        float4 p[4];
        #pragma unroll
        for (int k = 0; k < 4; k++) p[k] = *(const float4*)(x + xb + (size_t)t * NNv + 4 * k);
        const float* xp = (const float*)p;
        unsigned int ob[4] = {0, 0, 0, 0};
        #pragma unroll
        for (int i = 0; i < 16; i++) {
            float y = __fadd_rn(__fmul_rn(xp[i], inv), add);
            float vv = __fadd_rn(v[i], __fdiv_rn(__fsub_rn(y, v[i]), 1.5f));
            bool sp = vv >= 1.0f;
            v[i] = sp ? 0.0f : vv;
            if (sp) ob[i >> 2] |= 1u << (8 * (i & 3));
        }
        uint4 pk; pk.x = ob[0]; pk.y = ob[1]; pk.z = ob[2]; pk.w = ob[3];
        *(uint4*)&ts[t][cl][np * 16] = pk;
    }
    __syncthreads();
    int nl = tx >> 2, cp = tx & 3;
    #pragma unroll
    for (int t = 0; t < TT; t++) {
        unsigned int u[4];
        #pragma unroll
        for (int kk = 0; kk < 4; kk++) {
            u[kk] = (unsigned int)ts[t][cp * 16 + kk * 4 + 0][nl]
                  | ((unsigned int)ts[t][cp * 16 + kk * 4 + 1][nl] << 8)
                  | ((unsigned int)ts[t][cp * 16 + kk * 4 + 2][nl] << 16)
                  | ((unsigned int)ts[t][cp * 16 + kk * 4 + 3][nl] << 24);
        }
        uint4 pk; pk.x = u[0]; pk.y = u[1]; pk.z = u[2]; pk.w = u[3];
        *(uint4*)(s1T + ((size_t)(bl * TT + t) * NNv + n0 + nl) * CC + c0 + cp * 16) = pk;
    }
}

// ------- GEMM1 (fc1) i8 3-digit concurrent, byte-LDS, COALESCED s2T stores -------
// Tile 64h x 32n x 4t. R10 loop + (a) weight loads issued BEFORE the barrier so
// L2 latency hides under barrier+ds_read, (b) epilogue stages pk words in the
// (now dead) spike LDS and writes s2T as full 64B lines (was 4B/lane stride-1024
// scatter -> 2.9x write amplification, the hidden ~250us serializer).
__global__ __launch_bounds__(256, 3) void k_gemm1_lif(
    const unsigned char* __restrict__ w1d,
    const float* __restrict__ b1,
    const float* __restrict__ g1, const float* __restrict__ be1,
    const float* __restrict__ mu1, const float* __restrict__ va1,
    const unsigned char* __restrict__ s1T, unsigned char* __restrict__ s2T)
{
    __shared__ unsigned char Lsraw[TT * 32 * 80];  // 10,240 B; reused by epilogue
    const int tx = threadIdx.x;
    const int n0 = blockIdx.x * 32;
    const int ht = blockIdx.y;                     // h0 = ht*64
    const int bl = blockIdx.z;
    const int lane = tx & 63, w = tx >> 6;
    const int q = lane >> 4, ln = lane & 15;
    const int mh = (w & 1) * 32, wn = (w >> 1) * 16;
    const int h0 = ht * 64;

    int4v a0[TT][2], a1[TT][2], a2[TT][2];         // [t][mi] per digit
    #pragma unroll
    for (int t = 0; t < TT; t++)
    #pragma unroll
    for (int mi = 0; mi < 2; mi++) {
        a0[t][mi] = (int4v){0, 0, 0, 0};
        a1[t][mi] = (int4v){0, 0, 0, 0};
        a2[t][mi] = (int4v){0, 0, 0, 0};
    }

    // stage tasks: 4/thread covering 4t x 32n x 64c bytes (1024 x 8B)
    unsigned long long d[2][4];
    #pragma unroll
    for (int i = 0; i < 4; i++) {
        int task = i * 256 + tx;
        int cb = task & 7, nr = (task >> 3) & 31, t = task >> 8;
        d[0][i] = *(const unsigned long long*)(
            s1T + ((size_t)(bl * TT + t) * NNv + n0 + nr) * CC + 0 * 64 + cb * 8);
    }

    #pragma unroll
    for (int ko = 0; ko < 4; ko++) {
        const int cur = ko & 1;
        if (ko > 0) barrier_keep_vmem();           // prior ds_reads done (lgkm 0)
        #pragma unroll
        for (int i = 0; i < 4; i++) {
            int task = i * 256 + tx;
            int cb = task & 7, nr = (task >> 3) & 31, t = task >> 8;
            *(unsigned long long*)(Lsraw + (t * 32 + nr) * 80 + cb * 8) = d[cur][i];
        }
        if (ko < 3) {
            #pragma unroll
            for (int i = 0; i < 4; i++) {
                int task = i * 256 + tx;
                int cb = task & 7, nr = (task >> 3) & 31, t = task >> 8;
                d[cur ^ 1][i] = *(const unsigned long long*)(
                    s1T + ((size_t)(bl * TT + t) * NNv + n0 + nr) * CC + (ko + 1) * 64 + cb * 8);
            }
        }
        // weight loads for THIS ko issued BEFORE the barrier (no LDS dep);
        // they stay in flight across it -> L2 latency hidden.
        int4v w0[2], w1[2], w2[2];
        #pragma unroll
        for (int mi = 0; mi < 2; mi++) {
            size_t fb = ((((size_t)ht * 4 + ko) * 4 + (mh >> 4) + mi) << 10) + lane * 16;
            w0[mi] = *(const int4v*)(w1d + fb);
            w1[mi] = *(const int4v*)(w1d + 262144 + fb);
            w2[mi] = *(const int4v*)(w1d + 2 * 262144 + fb);
        }
        barrier_keep_vmem();

        int4v sf[TT];
        #pragma unroll
        for (int t = 0; t < TT; t++)
            sf[t] = *(const int4v*)(Lsraw + (t * 32 + wn + ln) * 80 + q * 16);
        #pragma unroll
        for (int t = 0; t < TT; t++)
        #pragma unroll
        for (int mi = 0; mi < 2; mi++) {
            a0[t][mi] = __builtin_amdgcn_mfma_i32_16x16x64_i8(w0[mi], sf[t], a0[t][mi], 0, 0, 0);
            a1[t][mi] = __builtin_amdgcn_mfma_i32_16x16x64_i8(w1[mi], sf[t], a1[t][mi], 0, 0, 0);
            a2[t][mi] = __builtin_amdgcn_mfma_i32_16x16x64_i8(w2[mi], sf[t], a2[t][mi], 0, 0, 0);
        }
    }

    // ---- epilogue ----
    // all waves' sf reads are complete before their barrier arrival (each read
    // is consumed by an MFMA, lgkm-waited) -> safe to reuse Lsraw after barrier.
    barrier_keep_vmem();

    // pk words -> LDS as u32 at [t][l(32)][hword(16)+pad4] (row = 80B, reuse)
    const int l_loc = wn + ln;
    #pragma unroll
    for (int mi = 0; mi < 2; mi++) {
        float invr[4], addr_[4], biasr[4];
        #pragma unroll
        for (int r = 0; r < 4; r++) {
            int h = h0 + mh + mi * 16 + q * 4 + r;
            float rsq = __fdiv_rn(1.0f, __fsqrt_rn(__fadd_rn(va1[h], 1e-5f)));
            invr[r] = __fmul_rn(g1[h], rsq);
            addr_[r] = __fsub_rn(be1[h], __fmul_rn(mu1[h], invr[r]));
            biasr[r] = b1[h];
        }
        float v4[4] = {0.f, 0.f, 0.f, 0.f};
        #pragma unroll
        for (int t = 0; t < TT; t++) {
            int4v ci = (((a0[t][mi] << 8) + a1[t][mi]) << 8) + a2[t][mi];
            unsigned int pk = 0;
            #pragma unroll
            for (int r = 0; r < 4; r++) {
                float h1 = __fadd_rn(__fmul_rn((float)ci[r], 5.9604644775390625e-08f),
                                     biasr[r]);    // 2^-24
                float y  = __fadd_rn(__fmul_rn(h1, invr[r]), addr_[r]);
                float vv = __fadd_rn(v4[r], __fdiv_rn(__fsub_rn(y, v4[r]), 1.5f));
                bool sp = vv >= 1.0f;
                v4[r] = sp ? 0.0f : vv;
                if (sp) pk |= (1u << (8 * r));
            }
            *(unsigned int*)(Lsraw + (t * 32 + l_loc) * 80
                             + ((mh >> 2) + mi * 4 + q) * 4) = pk;
        }
    }
    __syncthreads();

    // coalesced writeback: 512 tasks of 16B; consecutive threads -> consecutive
    // 16B -> full 64B lines (block covers exactly bytes [h0, h0+64) per row).
    #pragma unroll
    for (int p = 0; p < 2; p++) {
        int task = p * 256 + tx;
        int t = task >> 7, l = (task >> 2) & 31, ch = task & 3;
        uint4 vv = *(const uint4*)(Lsraw + (t * 32 + l) * 80 + ch * 16);
        *(uint4*)(s2T + ((size_t)bl * LLv + t * NNv + n0 + l) * HH + h0 + ch * 16) = vv;
    }
}

// ------- GEMM2 (fc2) i8 2-digit concurrent, byte-LDS, 128c tile, fp32 out -------
// c-tile widened 64->128 (halves s2T re-reads); weight loads issued before the
// barrier like gemm1. Output stores were already line-coalesced.
__global__ __launch_bounds__(256, 3) void k_gemm2(
    const unsigned char* __restrict__ w2d,
    const float* __restrict__ b2c,
    const unsigned char* __restrict__ s2T, float* __restrict__ outp, int b0)
{
    __shared__ unsigned char Ls[64][144];          // 9,216 B
    const int tx = threadIdx.x;
    const int l0 = blockIdx.x * 64;
    const int ct = blockIdx.y;                     // c-base = ct*128
    const int bl = blockIdx.z;
    const int b  = b0 + bl;
    const int lane = tx & 63, w = tx >> 6;
    const int q = lane >> 4, ln = lane & 15;
    const int mc = w * 32;                         // c-offset within 128

    int4v a0[2][4], a1[2][4];                      // [mi][ni] per digit
    #pragma unroll
    for (int mi = 0; mi < 2; mi++)
    #pragma unroll
    for (int ni = 0; ni < 4; ni++) {
        a0[mi][ni] = (int4v){0, 0, 0, 0};
        a1[mi][ni] = (int4v){0, 0, 0, 0};
    }

    // stage tasks: 4/thread covering 64l x 128h bytes (1024 x 8B)
    unsigned long long d[2][4];
    #pragma unroll
    for (int i = 0; i < 4; i++) {
        int task = i * 256 + tx;
        int hb = task & 15, lr = task >> 4;
        d[0][i] = *(const unsigned long long*)(
            s2T + ((size_t)bl * LLv + l0 + lr) * HH + 0 * 128 + hb * 8);
    }

    #pragma unroll
    for (int ko = 0; ko < 8; ko++) {
        const int cur = ko & 1;
        if (ko > 0) barrier_keep_vmem();
        #pragma unroll
        for (int i = 0; i < 4; i++) {
            int task = i * 256 + tx;
            int hb = task & 15, lr = task >> 4;
            *(unsigned long long*)&Ls[lr][hb * 8] = d[cur][i];          // raw bytes
        }
        if (ko < 7) {
            #pragma unroll
            for (int i = 0; i < 4; i++) {
                int task = i * 256 + tx;
                int hb = task & 15, lr = task >> 4;
                d[cur ^ 1][i] = *(const unsigned long long*)(
                    s2T + ((size_t)bl * LLv + l0 + lr) * HH + (ko + 1) * 128 + hb * 8);
            }
        }
        // weight loads for THIS ko before the barrier (cross it in flight)
        int4v w0[2][2], w1[2][2];                  // [kb][mi]
        #pragma unroll
        for (int kb = 0; kb < 2; kb++)
        #pragma unroll
        for (int mi = 0; mi < 2; mi++) {
            size_t fb = (((((size_t)(ct * 2 + (w >> 1)) * 8 + ko) * 2 + kb) * 4
                          + (w & 1) * 2 + mi) << 10) + lane * 16;
            w0[kb][mi] = *(const int4v*)(w2d + fb);
            w1[kb][mi] = *(const int4v*)(w2d + 262144 + fb);
        }
        barrier_keep_vmem();

        #pragma unroll
        for (int kb = 0; kb < 2; kb++) {
            int4v sf[4];
            #pragma unroll
            for (int ni = 0; ni < 4; ni++)
                sf[ni] = *(const int4v*)&Ls[ni * 16 + ln][kb * 64 + q * 16];
            #pragma unroll
            for (int mi = 0; mi < 2; mi++)
            #pragma unroll
            for (int ni = 0; ni < 4; ni++) {
                a0[mi][ni] = __builtin_amdgcn_mfma_i32_16x16x64_i8(w0[kb][mi], sf[ni], a0[mi][ni], 0, 0, 0);
                a1[mi][ni] = __builtin_amdgcn_mfma_i32_16x16x64_i8(w1[kb][mi], sf[ni], a1[mi][ni], 0, 0, 0);
            }
        }
    }
    #pragma unroll
    for (int mi = 0; mi < 2; mi++)
    #pragma unroll
    for (int ni = 0; ni < 4; ni++) {
        int4v tv = (a0[mi][ni] << 8) + a1[mi][ni];
        #pragma unroll
        for (int r = 0; r < 4; r++) {
            int c = ct * 128 + mc + mi * 16 + q * 4 + r;
            int l = l0 + ni * 16 + ln;
            outp[((size_t)b * CC + c) * LLv + l] =
                __fadd_rn(__fmul_rn((float)tv[r], 1.52587890625e-05f), b2c[c]); // 2^-16
        }
    }
}

extern "C" void kernel_launch(void* const* d_in, const int* in_sizes, int n_in,
                              void* d_out, int out_size, void* d_ws, size_t ws_size,
                              hipStream_t stream) {
    const float* x    = (const float*)d_in[0];
    const float* fc1w = (const float*)d_in[1];
    const float* fc1b = (const float*)d_in[2];
    const float* fc2w = (const float*)d_in[3];
    const float* fc2b = (const float*)d_in[4];
    const float* g1   = (const float*)d_in[5];
    const float* be1  = (const float*)d_in[6];
    const float* mu1  = (const float*)d_in[7];
    const float* va1  = (const float*)d_in[8];
    const float* g2   = (const float*)d_in[9];
    const float* be2  = (const float*)d_in[10];
    const float* mu2  = (const float*)d_in[11];
    const float* va2  = (const float*)d_in[12];

    // Workspace layout (ws_size-adaptive; NEVER exceed ws_size — overflow
    // clobbers adjacent input allocations and corrupts x on later calls):
    //   w1d: 3*262144 i8 digits (768 KB)
    //   w2d: 2*262144 i8 digits (512 KB)
    //   s1T: (full? 8 : 1) * 4 MB      bn2+LIF spike bytes [b][t][n][c]
    //   s2T: nbc * 16.78 MB            layer-1 spike bytes [bl][l][h]
    const size_t WB  = (size_t)3 * 262144 + (size_t)2 * 262144;          // 1,310,720
    const size_t S1B = (size_t)TT * NNv * CC;                            // 4,194,304 per b
    const size_t S2B = (size_t)LLv * HH;                                 // 16,777,216 per b

    int nbc;          // batch elements per gemm1/gemm2 chunk
    bool full_s1;     // s1T holds all 8 batches (bn2 runs once)?
    if      (ws_size >= WB + 8 * S1B + 8 * S2B) { nbc = 8; full_s1 = true;  }
    else if (ws_size >= WB + 8 * S1B + 4 * S2B) { nbc = 4; full_s1 = true;  }
    else if (ws_size >= WB + 8 * S1B + 2 * S2B) { nbc = 2; full_s1 = true;  }
    else if (ws_size >= WB + 8 * S1B + 1 * S2B) { nbc = 1; full_s1 = true;  }
    else                                        { nbc = 1; full_s1 = false; }

    unsigned char* w1d = (unsigned char*)d_ws;
    unsigned char* w2d = w1d + (size_t)3 * 262144;
    unsigned char* s1T = w2d + (size_t)2 * 262144;
    unsigned char* s2T = s1T + (full_s1 ? (size_t)8 * S1B : S1B);
    float* outp = (float*)d_out;

    hipLaunchKernelGGL(k_prep1, dim3(1024), dim3(256), 0, stream, fc1w, w1d);
    hipLaunchKernelGGL(k_prep2, dim3(1024), dim3(256), 0, stream, fc2w, w2d);

    if (full_s1) {
        hipLaunchKernelGGL(k_bn2_lif_t, dim3(NNv / 64, CC / 64, BB), dim3(256), 0, stream,
                           x, g2, be2, mu2, va2, s1T, 0);
        for (int b0 = 0; b0 < BB; b0 += nbc) {
            hipLaunchKernelGGL(k_gemm1_lif, dim3(NNv / 32, HH / 64, nbc), dim3(256), 0, stream,
                               w1d, fc1b, g1, be1, mu1, va1, s1T + (size_t)b0 * S1B, s2T);
            hipLaunchKernelGGL(k_gemm2, dim3(LLv / 64, CC / 128, nbc), dim3(256), 0, stream,
                               w2d, fc2b, s2T, outp, b0);
        }
    } else {
        for (int b0 = 0; b0 < BB; ++b0) {
            hipLaunchKernelGGL(k_bn2_lif_t, dim3(NNv / 64, CC / 64, 1), dim3(256), 0, stream,
                               x, g2, be2, mu2, va2, s1T, b0);
            hipLaunchKernelGGL(k_gemm1_lif, dim3(NNv / 32, HH / 64, 1), dim3(256), 0, stream,
                               w1d, fc1b, g1, be1, mu1, va1, s1T, s2T);
            hipLaunchKernelGGL(k_gemm2, dim3(LLv / 64, CC / 128, 1), dim3(256), 0, stream,
                               w2d, fc2b, s2T, outp, b0);
        }
    }
}